// Round 6
// baseline (52.530 us; speedup 1.0000x reference)
//
#include <hip/hip_runtime.h>
#include <math.h>

// ChamferLoss: pc_src [B,3,M] f32, pc_dst [B,3,N] f32 -> scalar mean over (B,M)
// of min_n ||src_m - dst_n||.
//
// Identity: min_n d2 = |a|^2 + min_n (|b|^2 - 2 a.b).
// Per-dst float4 (-2bx,-2by,-2bz,|b|^2) staged in LDS -> inner loop is
// 3 FMA + half a v_min3 per pair (3.5 VALU lane-ops/pair, floor ~12 us).
//
// R5 -> R6: R5's launch_bounds(256,8)+SPT=8 spilled (64-VGPR cap). Back to
// bounds(256,4) and raise SPT to 16: per 2 dst points a wave now issues
// 2 ds_read_b128 broadcasts against 112 VALU instrs, so the shared DS pipe
// (the R3 limiter at SPT=8) drops to <=half the VALU pace -> VALU-bound.
// ~90 VGPR, no spill at 4 waves/SIMD. Grid 8x128=1024 blocks = 4 blocks/CU.
// Keep 2-dispatch structure: part-store (no init needed) + ticket/fixed-point
// scalar writeout.

#define TPB 256

constexpr int NB = 4;
constexpr int NM = 8192;
constexpr int NN = 8192;
constexpr int NSEG = 128;                         // dst segments
constexpr int SEG = NN / NSEG;                    // 64 dst per segment
constexpr int SPT = 16;                           // src points per thread
constexpr int SRC_PER_BLOCK = TPB * SPT;          // 4096
constexpr int NPTS = NB * NM;                     // 32768
constexpr int CHUNKS = NPTS / SRC_PER_BLOCK;      // 8
constexpr int CHUNKS_PER_B = NM / SRC_PER_BLOCK;  // 2
constexpr int FIN_TPB = 64;                       // one wave per finish block
constexpr int NBLK_F = NPTS / FIN_TPB;            // 512

// Kernel 1: per (src-chunk, dst-segment) block. Build the segment's dst4 in
// LDS, running min of (b^2 - 2 a.b) over 16 src points/thread, store partial.
__global__ __launch_bounds__(TPB, 4) void minseg_kernel(const float* __restrict__ src,
                                                        const float* __restrict__ dst,
                                                        float* __restrict__ part,
                                                        unsigned long long* __restrict__ sumfix,
                                                        unsigned* __restrict__ ticket) {
    __shared__ float4 sdst[SEG];                  // 1 KB

    int chunk = blockIdx.x % CHUNKS;
    int seg   = blockIdx.x / CHUNKS;
    int b  = chunk / CHUNKS_PER_B;
    int t  = threadIdx.x;

    if (blockIdx.x == 0 && t == 0) { *sumfix = 0ULL; *ticket = 0u; }

    if (t < SEG) {
        int n = seg * SEG + t;
        const float* p = dst + (size_t)b * 3 * NN;
        float x = p[n], y = p[NN + n], z = p[2 * NN + n];
        sdst[t] = make_float4(-2.0f * x, -2.0f * y, -2.0f * z,
                              fmaf(x, x, fmaf(y, y, z * z)));
    }

    int m0 = (chunk % CHUNKS_PER_B) * SRC_PER_BLOCK + t;
    const float* sp = src + (size_t)b * 3 * NM;

    float ax[SPT], ay[SPT], az[SPT], mn[SPT];
#pragma unroll
    for (int k = 0; k < SPT; ++k) {
        int m = m0 + k * TPB;
        ax[k] = sp[m];
        ay[k] = sp[NM + m];
        az[k] = sp[2 * NM + m];
        mn[k] = 3.4e38f;
    }
    __syncthreads();

    for (int j = 0; j < SEG; j += 2) {
        float4 d0 = sdst[j];                      // uniform -> LDS broadcast
        float4 d1 = sdst[j + 1];
#pragma unroll
        for (int k = 0; k < SPT; ++k) {
            float t0 = fmaf(az[k], d0.z, d0.w);
            t0 = fmaf(ay[k], d0.y, t0);
            t0 = fmaf(ax[k], d0.x, t0);
            float t1 = fmaf(az[k], d1.z, d1.w);
            t1 = fmaf(ay[k], d1.y, t1);
            t1 = fmaf(ax[k], d1.x, t1);
            mn[k] = fminf(fminf(mn[k], t0), t1);  // -> v_min3_f32
        }
    }

#pragma unroll
    for (int k = 0; k < SPT; ++k) {
        int gm = b * NM + m0 + k * TPB;
        part[(size_t)seg * NPTS + gm] = mn[k];    // coalesced store
    }
}

// Kernel 2: one wave per 64 src points: min over 128 segments, sqrt, wave
// tree-sum, deterministic fixed-point accumulate; last block writes out.
__global__ __launch_bounds__(FIN_TPB) void finish_kernel(const float* __restrict__ src,
                                                         const float* __restrict__ part,
                                                         unsigned long long* __restrict__ sumfix,
                                                         unsigned* __restrict__ ticket,
                                                         float* __restrict__ out) {
    int gm = blockIdx.x * FIN_TPB + threadIdx.x;
    int b = gm / NM, m = gm % NM;

    float v = fminf(part[gm], part[NPTS + gm]);
#pragma unroll 8
    for (int s = 2; s < NSEG; s += 2)
        v = fminf(fminf(v, part[(size_t)s * NPTS + gm]),
                  part[(size_t)(s + 1) * NPTS + gm]);   // -> v_min3_f32

    const float* sp = src + (size_t)b * 3 * NM;
    float x = sp[m], y = sp[NM + m], z = sp[2 * NM + m];
    float a2 = fmaf(x, x, fmaf(y, y, z * z));
    float d = sqrtf(fmaxf(a2 + v, 0.0f));

    for (int off = 32; off > 0; off >>= 1) d += __shfl_down(d, off);

    if (threadIdx.x == 0) {
        // Fixed-point (32.32) accumulate: integer adds are associative ->
        // deterministic regardless of block order.
        unsigned long long inc = (unsigned long long)((double)d * 4294967296.0);
        atomicAdd(sumfix, inc);
        __threadfence();                          // sum-add before ticket-add
        unsigned tk = atomicAdd(ticket, 1u);
        if (tk == NBLK_F - 1) {
            unsigned long long tot = atomicAdd(sumfix, 0ULL);  // coherent read
            out[0] = (float)((double)tot * (1.0 / 4294967296.0) * (1.0 / NPTS));
        }
    }
}

extern "C" void kernel_launch(void* const* d_in, const int* in_sizes, int n_in,
                              void* d_out, int out_size, void* d_ws, size_t ws_size,
                              hipStream_t stream) {
    const float* src = (const float*)d_in[0];   // [B,3,M]
    const float* dst = (const float*)d_in[1];   // [B,3,N]
    float* out = (float*)d_out;

    char* ws = (char*)d_ws;
    float* part = (float*)ws;                                        // 16 MB
    unsigned long long* sumfix =
        (unsigned long long*)(ws + (size_t)NSEG * NPTS * 4);         // 8 B
    unsigned* ticket = (unsigned*)(ws + (size_t)NSEG * NPTS * 4 + 8);// 4 B

    minseg_kernel<<<CHUNKS * NSEG, TPB, 0, stream>>>(src, dst, part, sumfix, ticket);
    finish_kernel<<<NBLK_F, FIN_TPB, 0, stream>>>(src, part, sumfix, ticket, out);
}

// Round 7
// 35.969 us; speedup vs baseline: 1.4604x; 1.4604x over previous
//
#include <hip/hip_runtime.h>
#include <math.h>

// ChamferLoss: pc_src [B,3,M] f32, pc_dst [B,3,N] f32 -> scalar mean over (B,M)
// of min_n ||src_m - dst_n||.
//
// Identity: min_n d2 = |a|^2 + min_n (|b|^2 - 2 a.b).
// Per-dst float4 (-2bx,-2by,-2bz,|b|^2) staged in LDS -> inner loop is
// 3 FMA + half a v_min3 per pair. Pure VALU-f32; inputs L2-resident.
//
// R6 -> R7: revert minseg to the R3 champion config exactly (NSEG=64/SEG=128,
// SPT=8, launch_bounds(256,4) -> ~50/128 VGPR headroom, j-unroll 4, LDS
// broadcast, atomicMin into 128 KB minenc). R5/R6 regressions attributed to
// register-cap spill (SPT=8@cap64, SPT=16@cap128). New: finish+final fused
// via ticket + fixed-point u64 accumulate (one dispatch + one gap saved);
// independent-first min order shortens the loop-carried mn chain.

#define TPB 256

constexpr int NB = 4;
constexpr int NM = 8192;
constexpr int NN = 8192;
constexpr int NSEG = 64;                          // dst segments
constexpr int SEG = NN / NSEG;                    // 128 dst per segment
constexpr int SPT = 8;                            // src points per thread
constexpr int SRC_PER_BLOCK = TPB * SPT;          // 2048
constexpr int NPTS = NB * NM;                     // 32768
constexpr int CHUNKS = NPTS / SRC_PER_BLOCK;      // 16
constexpr int CHUNKS_PER_B = NM / SRC_PER_BLOCK;  // 4
constexpr int NBLK_C = NPTS / TPB;                // 128

// Order-preserving float<->uint encode so unsigned atomicMin == float min.
__device__ __forceinline__ unsigned enc_f32(float f) {
    unsigned u = __float_as_uint(f);
    return (u & 0x80000000u) ? ~u : (u | 0x80000000u);
}
__device__ __forceinline__ float dec_f32(unsigned u) {
    unsigned b = (u & 0x80000000u) ? (u ^ 0x80000000u) : ~u;
    return __uint_as_float(b);
}

// Kernel 1: per (src-chunk, dst-segment) block. Build the segment's dst4 in
// LDS, running min of (b^2 - 2 a.b) over 8 src points/thread, atomicMin out.
__global__ __launch_bounds__(TPB, 4) void minseg_kernel(const float* __restrict__ src,
                                                        const float* __restrict__ dst,
                                                        unsigned* __restrict__ minenc,
                                                        unsigned long long* __restrict__ sumfix,
                                                        unsigned* __restrict__ ticket) {
    __shared__ float4 sdst[SEG];                  // 2 KB

    int chunk = blockIdx.x % CHUNKS;
    int seg   = blockIdx.x / CHUNKS;
    int b  = chunk / CHUNKS_PER_B;
    int t  = threadIdx.x;

    if (blockIdx.x == 0 && t == 0) { *sumfix = 0ULL; *ticket = 0u; }

    if (t < SEG) {
        int n = seg * SEG + t;
        const float* p = dst + (size_t)b * 3 * NN;
        float x = p[n], y = p[NN + n], z = p[2 * NN + n];
        sdst[t] = make_float4(-2.0f * x, -2.0f * y, -2.0f * z,
                              fmaf(x, x, fmaf(y, y, z * z)));
    }

    int m0 = (chunk % CHUNKS_PER_B) * SRC_PER_BLOCK + t;
    const float* sp = src + (size_t)b * 3 * NM;

    float ax[SPT], ay[SPT], az[SPT], mn[SPT];
#pragma unroll
    for (int k = 0; k < SPT; ++k) {
        int m = m0 + k * TPB;
        ax[k] = sp[m];
        ay[k] = sp[NM + m];
        az[k] = sp[2 * NM + m];
        mn[k] = 3.4e38f;
    }
    __syncthreads();

#pragma unroll 4
    for (int j = 0; j < SEG; j += 2) {
        float4 d0 = sdst[j];                      // uniform -> LDS broadcast
        float4 d1 = sdst[j + 1];
#pragma unroll
        for (int k = 0; k < SPT; ++k) {
            float t0 = fmaf(az[k], d0.z, d0.w);
            t0 = fmaf(ay[k], d0.y, t0);
            t0 = fmaf(ax[k], d0.x, t0);
            float t1 = fmaf(az[k], d1.z, d1.w);
            t1 = fmaf(ay[k], d1.y, t1);
            t1 = fmaf(ax[k], d1.x, t1);
            // independent-first: 1-op loop-carried chain on mn, fuses to min3
            mn[k] = fminf(fminf(t0, t1), mn[k]);
        }
    }

#pragma unroll
    for (int k = 0; k < SPT; ++k) {
        int gm = b * NM + m0 + k * TPB;
        atomicMin(&minenc[gm], enc_f32(mn[k]));   // exact, order-independent
    }
}

// Kernel 2: per src point, d = sqrt(max(a^2 + minval, 0)); block tree-sum;
// deterministic fixed-point accumulate; last block (ticket) writes scalar.
__global__ __launch_bounds__(TPB) void finish_kernel(const float* __restrict__ src,
                                                     const unsigned* __restrict__ minenc,
                                                     unsigned long long* __restrict__ sumfix,
                                                     unsigned* __restrict__ ticket,
                                                     float* __restrict__ out) {
    int gm = blockIdx.x * TPB + threadIdx.x;
    int b = gm / NM, m = gm % NM;
    const float* sp = src + (size_t)b * 3 * NM;
    float x = sp[m], y = sp[NM + m], z = sp[2 * NM + m];
    float a2 = fmaf(x, x, fmaf(y, y, z * z));
    float v = dec_f32(minenc[gm]);
    float d = sqrtf(fmaxf(a2 + v, 0.0f));

    for (int off = 32; off > 0; off >>= 1) d += __shfl_down(d, off);
    __shared__ float wsum[4];
    int lane = threadIdx.x & 63, w = threadIdx.x >> 6;
    if (lane == 0) wsum[w] = d;
    __syncthreads();

    if (threadIdx.x == 0) {
        float bs = (wsum[0] + wsum[1]) + (wsum[2] + wsum[3]);
        // Fixed-point (32.32) accumulate: integer adds are associative ->
        // deterministic regardless of block order.
        unsigned long long inc = (unsigned long long)((double)bs * 4294967296.0);
        atomicAdd(sumfix, inc);
        __threadfence();                          // sum-add before ticket-add
        unsigned tk = atomicAdd(ticket, 1u);
        if (tk == NBLK_C - 1) {
            unsigned long long tot = atomicAdd(sumfix, 0ULL);  // coherent read
            out[0] = (float)((double)tot * (1.0 / 4294967296.0) * (1.0 / NPTS));
        }
    }
}

extern "C" void kernel_launch(void* const* d_in, const int* in_sizes, int n_in,
                              void* d_out, int out_size, void* d_ws, size_t ws_size,
                              hipStream_t stream) {
    const float* src = (const float*)d_in[0];   // [B,3,M]
    const float* dst = (const float*)d_in[1];   // [B,3,N]
    float* out = (float*)d_out;

    char* ws = (char*)d_ws;
    unsigned* minenc = (unsigned*)ws;                                // 128 KB
    unsigned long long* sumfix =
        (unsigned long long*)(ws + (size_t)NPTS * 4);                // 8 B
    unsigned* ticket = (unsigned*)(ws + (size_t)NPTS * 4 + 8);       // 4 B

    hipMemsetAsync(minenc, 0xFF, (size_t)NPTS * 4, stream);          // > +inf
    minseg_kernel<<<CHUNKS * NSEG, TPB, 0, stream>>>(src, dst, minenc, sumfix, ticket);
    finish_kernel<<<NBLK_C, TPB, 0, stream>>>(src, minenc, sumfix, ticket, out);
}